// Round 6
// baseline (320.457 us; speedup 1.0000x reference)
//
#include <hip/hip_runtime.h>
#include <cstdint>
#include <cstddef>

#define B_    4096
#define H_    1024
#define NOBS  128
#define NDIR  64
#define MAXIT 10
#define LRI   1e-3f
#define TOLC  1e-3
#define KS_   8      // split-K factor for logits GEMM

typedef __bf16 bf16x8 __attribute__((ext_vector_type(8)));
typedef float  f32x4  __attribute__((ext_vector_type(4)));
typedef float  f32x16 __attribute__((ext_vector_type(16)));

__device__ __forceinline__ ushort f2bf(float x) {
    uint32_t u = __float_as_uint(x);
    u += 0x7FFFu + ((u >> 16) & 1u);   // RN-even to bf16
    return (ushort)(u >> 16);
}
__device__ __forceinline__ float bf2f(ushort h) {
    return __uint_as_float(((uint32_t)h) << 16);
}

// ---------------------------------------------------------------------------
// Stage one ROWSx32 bf16 tile into LDS via global_load_lds (16B/lane),
// with XOR-swizzled global source; LDS stays linear; reads apply same XOR.
// Each thread issues ROWS*4/256 loads (8 per 128-row tile per thread total
// across the 4 hi/lo A/B calls).
// ---------------------------------------------------------------------------
template<int ROWS>
__device__ __forceinline__ void stage_tile(ushort* dst, const ushort* src,
                                           size_t rowbase, int ld, int k0,
                                           int tid, int wid)
{
    constexpr int ITERS = ROWS * 4 / 256;
#pragma unroll
    for (int cc = 0; cc < ITERS; ++cc) {
        const int c = cc * 256 + tid;
        const int r = c >> 2, s = c & 3;
        const int ks = ((s ^ ((r >> 1) & 3)) << 3);
        const ushort* g = src + (rowbase + r) * (size_t)ld + k0 + ks;
        __builtin_amdgcn_global_load_lds(
            (const __attribute__((address_space(1))) void*)g,
            (__attribute__((address_space(3))) void*)(dst + (cc * 256 + wid * 64) * 8),
            16, 0, 0);
    }
}

// ---------------------------------------------------------------------------
// EPI0 (dominant): O = relu(prev @ Wr^T + Win[col, dirs[row]]), bf16x3.
// 128x128 tile, 32x32x16 frags, wave=64x64 (2x2 frags), 4 waves.
// 3-buffer pipeline, counted vmcnt(8). Two barriers per K-step (m201
// discipline); sched_barrier(0) fences pin issue-order invariants:
//   - prologue fence keeps tile0's 8 loads strictly oldest for vmcnt(8)
//   - barrier#2 after MFMA guarantees all waves' reads of buf[t] are done
//     before any wave stages tile t+3 into that same buffer next step.
// ---------------------------------------------------------------------------
__global__ __launch_bounds__(256)
void wr_gemm_k(const ushort* __restrict__ Ahi, const ushort* __restrict__ Alo,
               const ushort* __restrict__ Bhi, const ushort* __restrict__ Blo,
               float* __restrict__ O,
               const int* __restrict__ dirs, const float* __restrict__ Win,
               const int* gate)
{
    if (gate && *gate == 0) return;

    constexpr int NST = H_ / 32;        // 32 K-steps
    __shared__ ushort sA[3][2][128 * 32];
    __shared__ ushort sB[3][2][128 * 32];

    const int tid = threadIdx.x, lane = tid & 63, wid = tid >> 6;
    const size_t m0 = (size_t)blockIdx.y * 128;
    const size_t n0 = (size_t)blockIdx.x * 128;
    const int wr = wid >> 1, wc = wid & 1;

    f32x16 acc[2][2];
#pragma unroll
    for (int i = 0; i < 2; ++i)
#pragma unroll
        for (int j = 0; j < 2; ++j)
#pragma unroll
            for (int r = 0; r < 16; ++r) acc[i][j][r] = 0.f;

    // prologue: stage tiles 0 and 1; fence so tile0's loads stay oldest
    stage_tile<128>(sA[0][0], Ahi, m0, H_, 0, tid, wid);
    stage_tile<128>(sA[0][1], Alo, m0, H_, 0, tid, wid);
    stage_tile<128>(sB[0][0], Bhi, n0, H_, 0, tid, wid);
    stage_tile<128>(sB[0][1], Blo, n0, H_, 0, tid, wid);
    __builtin_amdgcn_sched_barrier(0);   // pin: tile0's 8 loads issued first
    stage_tile<128>(sA[1][0], Ahi, m0, H_, 32, tid, wid);
    stage_tile<128>(sA[1][1], Alo, m0, H_, 32, tid, wid);
    stage_tile<128>(sB[1][0], Bhi, n0, H_, 32, tid, wid);
    stage_tile<128>(sB[1][1], Blo, n0, H_, 32, tid, wid);
    __builtin_amdgcn_sched_barrier(0);

    int cur = 0;
#pragma unroll 1
    for (int t = 0; t < NST; ++t) {
        // my 8 loads for buf[t] have landed (tile t+1's 8 may stay in flight)
        if (t + 1 < NST) asm volatile("s_waitcnt vmcnt(8)" ::: "memory");
        else             asm volatile("s_waitcnt vmcnt(0)" ::: "memory");
        __builtin_amdgcn_sched_barrier(0);
        __builtin_amdgcn_s_barrier();      // all waves' buf[t] writes visible
        __builtin_amdgcn_sched_barrier(0);

        if (t + 2 < NST) {                 // stage tile t+2 into buf[(t+2)%3]
            const int nbuf = (cur >= 1) ? cur - 1 : cur + 2;
            const int k0 = (t + 2) * 32;
            stage_tile<128>(sA[nbuf][0], Ahi, m0, H_, k0, tid, wid);
            stage_tile<128>(sA[nbuf][1], Alo, m0, H_, k0, tid, wid);
            stage_tile<128>(sB[nbuf][0], Bhi, n0, H_, k0, tid, wid);
            stage_tile<128>(sB[nbuf][1], Blo, n0, H_, k0, tid, wid);
        }
        __builtin_amdgcn_sched_barrier(0); // stage issue precedes ds_reads

        const ushort* pAh = sA[cur][0];
        const ushort* pAl = sA[cur][1];
        const ushort* pBh = sB[cur][0];
        const ushort* pBl = sB[cur][1];

#pragma unroll
        for (int s = 0; s < 2; ++s) {      // two K=16 slices per step
            bf16x8 ah[2], al[2], bh[2], bl[2];
            const int e8 = s * 2 + (lane >> 5);
#pragma unroll
            for (int mb = 0; mb < 2; ++mb) {
                const int row = wr * 64 + mb * 32 + (lane & 31);
                const int off = row * 32 + ((e8 ^ ((row >> 1) & 3)) << 3);
                ah[mb] = *(const bf16x8*)&pAh[off];
                al[mb] = *(const bf16x8*)&pAl[off];
            }
#pragma unroll
            for (int nb = 0; nb < 2; ++nb) {
                const int row = wc * 64 + nb * 32 + (lane & 31);
                const int off = row * 32 + ((e8 ^ ((row >> 1) & 3)) << 3);
                bh[nb] = *(const bf16x8*)&pBh[off];
                bl[nb] = *(const bf16x8*)&pBl[off];
            }
#pragma unroll
            for (int mb = 0; mb < 2; ++mb)
#pragma unroll
                for (int nb = 0; nb < 2; ++nb) {
                    acc[mb][nb] = __builtin_amdgcn_mfma_f32_32x32x16_bf16(ah[mb], bh[nb], acc[mb][nb], 0, 0, 0);
                    acc[mb][nb] = __builtin_amdgcn_mfma_f32_32x32x16_bf16(ah[mb], bl[nb], acc[mb][nb], 0, 0, 0);
                    acc[mb][nb] = __builtin_amdgcn_mfma_f32_32x32x16_bf16(al[mb], bh[nb], acc[mb][nb], 0, 0, 0);
                }
        }

        __builtin_amdgcn_sched_barrier(0);
        __builtin_amdgcn_s_barrier();      // barrier#2: block-wide reads of buf[t] done
        cur = (cur == 2) ? 0 : cur + 1;
    }

    // epilogue: 32x32 C/D layout row=(reg&3)+8*(reg>>2)+4*(lane>>5), col=lane&31
#pragma unroll
    for (int mb = 0; mb < 2; ++mb)
#pragma unroll
        for (int reg = 0; reg < 16; ++reg) {
            const size_t row = m0 + wr * 64 + mb * 32 +
                               (reg & 3) + 8 * (reg >> 2) + 4 * (lane >> 5);
            const int dd = dirs[row];
#pragma unroll
            for (int nb = 0; nb < 2; ++nb) {
                const size_t col = n0 + wc * 64 + nb * 32 + (lane & 31);
                const float v = acc[mb][nb][reg] + Win[col * NDIR + dd];
                O[row * H_ + col] = fmaxf(v, 0.f);
            }
        }
}

// ---------------------------------------------------------------------------
// Secondary bf16x3 MFMA GEMM (16x16 frags, 2-buffer, __syncthreads drain —
// proven race-free), for the thin products.
// EPI 1: part[bx] = A@B^T K-chunk partial             (logits split-K, BN=128)
// EPI 2: T = Cin + LRI*((T - Cin) + A@B^T)            (update GEMM, BN=64)
// ---------------------------------------------------------------------------
template<int EPI, int BN>
__global__ __launch_bounds__(256)
void gemm_pipe_k(const ushort* __restrict__ Ahi, const ushort* __restrict__ Alo, int lda,
                 const ushort* __restrict__ Bhi, const ushort* __restrict__ Blo, int ldb,
                 float* __restrict__ O,
                 const float* __restrict__ Cin,
                 const int* gate)
{
    if (gate && *gate == 0) return;

    constexpr int NFR = BN / 32;
    constexpr int NST = (EPI == 1) ? (H_ / KS_) / 32 : NOBS / 32;

    __shared__ ushort sA[2][2][128 * 32];
    __shared__ ushort sB[2][2][BN * 32];

    const int tid = threadIdx.x, lane = tid & 63, wid = tid >> 6;
    const size_t m0  = (size_t)blockIdx.y * 128;
    const size_t bn0 = (EPI == 1) ? 0 : (size_t)blockIdx.x * BN;
    const int kbase  = (EPI == 1) ? blockIdx.x * (H_ / KS_) : 0;
    const int wr = wid >> 1, wc = wid & 1;

    f32x4 acc[4][NFR];
#pragma unroll
    for (int i = 0; i < 4; ++i)
#pragma unroll
        for (int j = 0; j < NFR; ++j) acc[i][j] = (f32x4){0.f, 0.f, 0.f, 0.f};

    const int rsel = lane & 15;
    const int kb   = lane >> 4;

    stage_tile<128>(sA[0][0], Ahi, m0, lda, kbase, tid, wid);
    stage_tile<128>(sA[0][1], Alo, m0, lda, kbase, tid, wid);
    stage_tile<BN >(sB[0][0], Bhi, bn0, ldb, kbase, tid, wid);
    stage_tile<BN >(sB[0][1], Blo, bn0, ldb, kbase, tid, wid);
    __syncthreads();

#pragma unroll
    for (int t = 0; t < NST; ++t) {
        const int cur = t & 1;
        if (t + 1 < NST) {
            const int k0 = kbase + (t + 1) * 32;
            stage_tile<128>(sA[cur ^ 1][0], Ahi, m0, lda, k0, tid, wid);
            stage_tile<128>(sA[cur ^ 1][1], Alo, m0, lda, k0, tid, wid);
            stage_tile<BN >(sB[cur ^ 1][0], Bhi, bn0, ldb, k0, tid, wid);
            stage_tile<BN >(sB[cur ^ 1][1], Blo, bn0, ldb, k0, tid, wid);
        }

        bf16x8 ah[4], al[4], bh[NFR], bl[NFR];
#pragma unroll
        for (int f = 0; f < 4; ++f) {
            const int arow = wr * 64 + f * 16 + rsel;
            const int aoff = arow * 32 + ((kb ^ ((arow >> 1) & 3)) << 3);
            ah[f] = *(const bf16x8*)&sA[cur][0][aoff];
            al[f] = *(const bf16x8*)&sA[cur][1][aoff];
        }
#pragma unroll
        for (int f = 0; f < NFR; ++f) {
            const int brow = wc * (BN / 2) + f * 16 + rsel;
            const int boff = brow * 32 + ((kb ^ ((brow >> 1) & 3)) << 3);
            bh[f] = *(const bf16x8*)&sB[cur][0][boff];
            bl[f] = *(const bf16x8*)&sB[cur][1][boff];
        }

#pragma unroll
        for (int i = 0; i < 4; ++i)
#pragma unroll
            for (int j = 0; j < NFR; ++j) {
                acc[i][j] = __builtin_amdgcn_mfma_f32_16x16x32_bf16(ah[i], bh[j], acc[i][j], 0, 0, 0);
                acc[i][j] = __builtin_amdgcn_mfma_f32_16x16x32_bf16(ah[i], bl[j], acc[i][j], 0, 0, 0);
                acc[i][j] = __builtin_amdgcn_mfma_f32_16x16x32_bf16(al[i], bh[j], acc[i][j], 0, 0, 0);
            }
        __syncthreads();
    }

    float* pout = (EPI == 1) ? O + (size_t)blockIdx.x * B_ * NOBS : O;
#pragma unroll
    for (int i = 0; i < 4; ++i) {
#pragma unroll
        for (int r = 0; r < 4; ++r) {
            const size_t row = m0 + wr * 64 + i * 16 + (lane >> 4) * 4 + r;
#pragma unroll
            for (int j = 0; j < NFR; ++j) {
                const size_t col = bn0 + wc * (BN / 2) + j * 16 + (lane & 15);
                if (EPI == 1) {
                    pout[row * NOBS + col] = acc[i][j][r];
                } else {
                    const size_t idx = row * H_ + col;
                    const float c = Cin[idx], rv = pout[idx];
                    pout[idx] = c + LRI * ((rv - c) + acc[i][j][r]);
                }
            }
        }
    }
}

// ---------------------------------------------------------------------------
// Reduce split-K partials -> logits; softmax.
// MODE 0: + Jacobian-vector product, write Jv bf16 split (gated).
// MODE 1: write probabilities to out (ungated, final).
// ---------------------------------------------------------------------------
template<int MODE>
__global__ __launch_bounds__(256)
void softjv_k(const float* __restrict__ part, const int* __restrict__ obs,
              ushort* __restrict__ Jhi, ushort* __restrict__ Jlo,
              float* __restrict__ probs, const int* gate)
{
    if (MODE == 0 && gate && *gate == 0) return;
    const int wid = threadIdx.x >> 6, lane = threadIdx.x & 63;
    const int b = blockIdx.x * 4 + wid;
    float x0 = 0.f, x1 = 0.f;
#pragma unroll
    for (int kb = 0; kb < KS_; ++kb) {
        const float* p = part + ((size_t)kb * B_ + b) * NOBS;
        x0 += p[lane]; x1 += p[lane + 64];
    }
    float mx = fmaxf(x0, x1);
#pragma unroll
    for (int off = 32; off > 0; off >>= 1) mx = fmaxf(mx, __shfl_xor(mx, off, 64));
    const float e0 = expf(x0 - mx), e1 = expf(x1 - mx);
    float s = e0 + e1;
#pragma unroll
    for (int off = 32; off > 0; off >>= 1) s += __shfl_xor(s, off, 64);
    const float f0 = e0 / s, f1 = e1 / s;
    if (MODE == 1) {
        probs[(size_t)b * NOBS + lane]      = f0;
        probs[(size_t)b * NOBS + lane + 64] = f1;
        return;
    }
    const int o = obs[b];
    const float ep0 = ((lane == o) ? 1.f : 0.f) - f0;
    const float ep1 = ((lane + 64 == o) ? 1.f : 0.f) - f1;
    float d = f0 * ep0 + f1 * ep1;
#pragma unroll
    for (int off = 32; off > 0; off >>= 1) d += __shfl_xor(d, off, 64);
    const float j0 = f0 * (ep0 - d), j1 = f1 * (ep1 - d);
    const ushort h0 = f2bf(j0), h1 = f2bf(j1);
    Jhi[(size_t)b * NOBS + lane]      = h0;
    Jlo[(size_t)b * NOBS + lane]      = f2bf(j0 - bf2f(h0));
    Jhi[(size_t)b * NOBS + lane + 64] = h1;
    Jlo[(size_t)b * NOBS + lane + 64] = f2bf(j1 - bf2f(h1));
}

// ---------------------------------------------------------------------------
// Fused advance + row-normalize (+ per-row sums for the convergence gate).
// ---------------------------------------------------------------------------
template<bool ADV>
__global__ __launch_bounds__(256)
void normadv_k(const float* __restrict__ T, float* __restrict__ C,
               ushort* __restrict__ Chi, ushort* __restrict__ Clo,
               ushort* __restrict__ Phi, ushort* __restrict__ Plo,
               const float* __restrict__ oldsum, float* __restrict__ rowsum,
               double* __restrict__ rowpart, const int* gate)
{
    if (gate && *gate == 0) return;
    const int b = blockIdx.x, tid = threadIdx.x;
    const size_t ro = (size_t)b * H_;

    if (ADV) {
        ((ushort4*)(Phi + ro))[tid] = ((const ushort4*)(Chi + ro))[tid];
        ((ushort4*)(Plo + ro))[tid] = ((const ushort4*)(Clo + ro))[tid];
    }

    const float4 v = ((const float4*)(T + ro))[tid];
    float ss = v.x * v.x + v.y * v.y + v.z * v.z + v.w * v.w;
    float sm = v.x + v.y + v.z + v.w;
#pragma unroll
    for (int off = 32; off > 0; off >>= 1) {
        ss += __shfl_down(ss, off, 64);
        sm += __shfl_down(sm, off, 64);
    }
    __shared__ float w1[4], w2[4];
    const int lane = tid & 63, wid = tid >> 6;
    if (lane == 0) { w1[wid] = ss; w2[wid] = sm; }
    __syncthreads();
    const float tot = w1[0] + w1[1] + w1[2] + w1[3];
    const float smt = w2[0] + w2[1] + w2[2] + w2[3];
    const float d = sqrtf(tot) + 1e-6f;

    float4 o;
    o.x = v.x / d; o.y = v.y / d; o.z = v.z / d; o.w = v.w / d;
    ((float4*)(C + ro))[tid] = o;
    ushort4 h, l;
    h.x = f2bf(o.x); l.x = f2bf(o.x - bf2f(h.x));
    h.y = f2bf(o.y); l.y = f2bf(o.y - bf2f(h.y));
    h.z = f2bf(o.z); l.z = f2bf(o.z - bf2f(h.z));
    h.w = f2bf(o.w); l.w = f2bf(o.w - bf2f(h.w));
    ((ushort4*)(Chi + ro))[tid] = h;
    ((ushort4*)(Clo + ro))[tid] = l;

    if (tid == 0) {
        const float news = smt / d;
        rowpart[b] = (double)oldsum[b] - (double)news;
        rowsum[b]  = news;
    }
}

// finalize cond: reduce 4096 row partials, set active/done (sticky)
__global__ __launch_bounds__(256)
void cond_fin_k(const double* __restrict__ rowpart, int* active, int* done)
{
    if (*done) { if (threadIdx.x == 0) *active = 0; return; }
    __shared__ double wsum[4];
    double s = 0.0;
    for (int i = threadIdx.x; i < B_; i += 256) s += rowpart[i];
#pragma unroll
    for (int off = 32; off > 0; off >>= 1) s += __shfl_down(s, off, 64);
    const int lane = threadIdx.x & 63, wid = threadIdx.x >> 6;
    if (lane == 0) wsum[wid] = s;
    __syncthreads();
    if (threadIdx.x == 0) {
        const double mean = (wsum[0] + wsum[1] + wsum[2] + wsum[3]) / (double)((size_t)B_ * H_);
        const int c = (fabs(mean) > TOLC) ? 1 : 0;
        *active = c;
        if (!c) *done = 1;
    }
}

// fp32 -> (hi,lo) bf16 split, flat (for Wr)
__global__ __launch_bounds__(256)
void split_k(const float* __restrict__ x, ushort* __restrict__ hi,
             ushort* __restrict__ lo)
{
    const size_t i = (size_t)blockIdx.x * 256 + threadIdx.x;
    const float4 v = ((const float4*)x)[i];
    ushort4 h, l;
    h.x = f2bf(v.x); l.x = f2bf(v.x - bf2f(h.x));
    h.y = f2bf(v.y); l.y = f2bf(v.y - bf2f(h.y));
    h.z = f2bf(v.z); l.z = f2bf(v.z - bf2f(h.z));
    h.w = f2bf(v.w); l.w = f2bf(v.w - bf2f(h.w));
    ((ushort4*)hi)[i] = h;
    ((ushort4*)lo)[i] = l;
}

// prev0: split + per-row sum
__global__ __launch_bounds__(256)
void prev0_prep_k(const float* __restrict__ prev0, ushort* __restrict__ Phi,
                  ushort* __restrict__ Plo, float* __restrict__ prevsum0)
{
    const int b = blockIdx.x, tid = threadIdx.x;
    const size_t ro = (size_t)b * H_;
    const float4 v = ((const float4*)(prev0 + ro))[tid];
    ushort4 h, l;
    h.x = f2bf(v.x); l.x = f2bf(v.x - bf2f(h.x));
    h.y = f2bf(v.y); l.y = f2bf(v.y - bf2f(h.y));
    h.z = f2bf(v.z); l.z = f2bf(v.z - bf2f(h.z));
    h.w = f2bf(v.w); l.w = f2bf(v.w - bf2f(h.w));
    ((ushort4*)(Phi + ro))[tid] = h;
    ((ushort4*)(Plo + ro))[tid] = l;
    float sm = v.x + v.y + v.z + v.w;
#pragma unroll
    for (int off = 32; off > 0; off >>= 1) sm += __shfl_down(sm, off, 64);
    __shared__ float w2[4];
    const int lane = tid & 63, wid = tid >> 6;
    if (lane == 0) w2[wid] = sm;
    __syncthreads();
    if (tid == 0) prevsum0[b] = w2[0] + w2[1] + w2[2] + w2[3];
}

// Wout: split + transposed split (once)
__global__ __launch_bounds__(256)
void prep_wout_k(const float* __restrict__ Wout, ushort* __restrict__ Whi,
                 ushort* __restrict__ Wlo, ushort* __restrict__ WThi,
                 ushort* __restrict__ WTlo)
{
    const int idx = blockIdx.x * 256 + threadIdx.x;   // < NOBS*H_
    const float w = Wout[idx];
    const ushort h = f2bf(w), l = f2bf(w - bf2f(h));
    Whi[idx] = h; Wlo[idx] = l;
    const int o = idx >> 10, hh = idx & 1023;
    WThi[(size_t)hh * NOBS + o] = h;
    WTlo[(size_t)hh * NOBS + o] = l;
}

__global__ __launch_bounds__(256)
void copy_k(const float* __restrict__ src, float* __restrict__ dst)
{
    const size_t i = (size_t)blockIdx.x * 256 + threadIdx.x;
    ((float4*)dst)[i] = ((const float4*)src)[i];
}

__global__ void flags_init_k(int* flags) { flags[0] = 0; flags[1] = 0; }

// ---------------------------------------------------------------------------
extern "C" void kernel_launch(void* const* d_in, const int* in_sizes, int n_in,
                              void* d_out, int out_size, void* d_ws, size_t ws_size,
                              hipStream_t stream)
{
    const int*   dirs  = (const int*)d_in[0];
    const int*   obs   = (const int*)d_in[1];
    const float* Wr    = (const float*)d_in[2];
    const float* Win   = (const float*)d_in[3];
    const float* Wout  = (const float*)d_in[4];
    const float* prev0 = (const float*)d_in[5];
    float* out = (float*)d_out;

    const size_t SZ = (size_t)B_ * H_;
    float*  C    = (float*)d_ws;
    float*  T    = C + SZ;
    float*  part = T + SZ;                        // KS_ * B_ * NOBS
    ushort* Chi  = (ushort*)(part + (size_t)KS_ * B_ * NOBS);
    ushort* Clo  = Chi + SZ;
    ushort* Phi  = Clo + SZ;
    ushort* Plo  = Phi + SZ;
    ushort* Wrhi = Plo + SZ;
    ushort* Wrlo = Wrhi + (size_t)H_ * H_;
    ushort* Whi  = Wrlo + (size_t)H_ * H_;
    ushort* Wlo  = Whi + (size_t)NOBS * H_;
    ushort* WThi = Wlo + (size_t)NOBS * H_;
    ushort* WTlo = WThi + (size_t)H_ * NOBS;
    ushort* Jhi  = WTlo + (size_t)H_ * NOBS;
    ushort* Jlo  = Jhi + (size_t)B_ * NOBS;
    double* rowpart = (double*)(Jlo + (size_t)B_ * NOBS);
    float* prevsum0 = (float*)(rowpart + B_);
    float* rowsumC  = prevsum0 + B_;
    int* flags  = (int*)(rowsumC + B_);
    int* done   = flags;
    int* active = flags + 1;

    const dim3 blk(256);
    const dim3 gBig(H_ / 128, B_ / 128);   // 256 blocks, 128x128 tile
    const dim3 gUpd(H_ / 64, B_ / 128);    // 512 blocks, BN=64
    const dim3 gLog(KS_, B_ / 128);        // 256 blocks, BN=128

    flags_init_k<<<1, 1, 0, stream>>>(flags);
    split_k<<<(H_ * H_ / 4) / 256, blk, 0, stream>>>(Wr, Wrhi, Wrlo);
    prev0_prep_k<<<B_, blk, 0, stream>>>(prev0, Phi, Plo, prevsum0);
    prep_wout_k<<<(NOBS * H_) / 256, blk, 0, stream>>>(Wout, Whi, Wlo, WThi, WTlo);

    // initial: T = relu(Wr@prev0 + drive); C = norm(T) (+ split + rowsums)
    wr_gemm_k<<<gBig, blk, 0, stream>>>(Phi, Plo, Wrhi, Wrlo, T, dirs, Win, nullptr);
    normadv_k<false><<<B_, blk, 0, stream>>>(
        T, C, Chi, Clo, nullptr, nullptr, prevsum0, rowsumC, rowpart, nullptr);

    for (int it = 0; it < MAXIT; ++it) {
        cond_fin_k<<<1, blk, 0, stream>>>(rowpart, active, done);

        // R = relu(Wr@prev + drive) -> T.  At it==0, T already holds R_0.
        if (it > 0)
            wr_gemm_k<<<gBig, blk, 0, stream>>>(Phi, Plo, Wrhi, Wrlo, T, dirs, Win, active);
        // logits partials from cur
        gemm_pipe_k<1, 128><<<gLog, blk, 0, stream>>>(
            Chi, Clo, H_, Whi, Wlo, H_, part, nullptr, active);
        // reduce + softmax + Jv (bf16 split)
        softjv_k<0><<<B_ / 4, blk, 0, stream>>>(part, obs, Jhi, Jlo, nullptr, active);
        // T = C + lr*((T - C) + Jv @ WoutT)
        gemm_pipe_k<2, 64><<<gUpd, blk, 0, stream>>>(
            Jhi, Jlo, NOBS, WThi, WTlo, NOBS, T, C, active);
        // prev <- cur (split copy); C <- norm(T); rowparts for next cond
        normadv_k<true><<<B_, blk, 0, stream>>>(
            T, C, Chi, Clo, Phi, Plo, rowsumC, rowsumC, rowpart, active);
    }

    // outputs: softmax(Wout @ cur), then cur
    gemm_pipe_k<1, 128><<<gLog, blk, 0, stream>>>(
        Chi, Clo, H_, Whi, Wlo, H_, part, nullptr, nullptr);
    softjv_k<1><<<B_ / 4, blk, 0, stream>>>(part, obs, nullptr, nullptr, out, nullptr);
    copy_k<<<SZ / 4 / 256, blk, 0, stream>>>(C, out + (size_t)B_ * NOBS);
}